// Round 7
// baseline (195.990 us; speedup 1.0000x reference)
//
#include <hip/hip_runtime.h>
#include <hip/hip_bf16.h>
#include <utility>

// fUpModule CG tensor product, MAXL=5, TAUS=OUT_TAUS=8, BATCH=1024, fp32 I/O.
// R11: R10 with the epilogue lane-coverage bug fixed (8*TW can be up to 88
// elements > 64 lanes; now a lane-strided loop). Structure:
//   - 1024-thread blocks (16 waves), one block per batch row;
//   - stage-1 triples greedy-balanced over 16 waves;
//   - stage-2: o-split over 8 waves x T-half split over 2 -> acc[TW] for
//     ONE o per wave (register pressure halved vs R4);
//   - reduce: 6-step butterfly per wave -> LDS redbuf (parity ping-pong)
//     -> wave 15 combines (o, o+8) in the next barrier region.
// Why: R9 proved block residency does NOT rise with more small blocks
// (occupancy pinned ~32%); waves-per-block is the residency lever:
// 2 x 1024-thread blocks = 32 waves/CU = HW thread-limit max.
// R5-R8 lessons: no asm barriers, no register arrays through lambda refs,
// no launch_bounds register caps below need; stage-2 loads stay in-loop.

constexpr int NTRIP = 69;
constexpr int NL    = 6;
constexpr int BATCH = 1024;
constexpr int ROW   = 288;     // complex elements per activation/output row
constexpr int MID_LDS = 4224;  // float2 slots for mid buffer
constexpr int NWAVES  = 16;

struct Meta {
    int tl1[NTRIP], tl2[NTRIP], tll[NTRIP];
    int tf1[NTRIP], tf2[NTRIP];   // complex offsets of F[l1], F[l2] blocks
    int ttloc[NTRIP];             // T start of this triple within its l group
    int trip_of_l[NL][16];
    int ntrips[NL];
    int mid_tau[NL], std_off[NL], w_off[NL], f_l[NL];
    int nch[NL];
    int ch_start[NL][2], ch_cnt[NL][2];
    int wave_of[NL][16];
};

constexpr Meta build_meta() {
    Meta m{};
    int fl[NL] = {};
    {
        int acc = 0;
        for (int l = 0; l < NL; l++) { fl[l] = acc; m.f_l[l] = acc; acc += 8 * (2 * l + 1); }
    }
    int idx = 0;
    for (int l1 = 0; l1 <= 5; l1++)
        for (int l2 = 0; l2 <= l1; l2++) {
            int lmax = (l1 + l2 < 5) ? (l1 + l2) : 5;
            for (int l = l1 - l2; l <= lmax; l++) {
                m.tl1[idx] = l1; m.tl2[idx] = l2; m.tll[idx] = l;
                m.tf1[idx] = fl[l1]; m.tf2[idx] = fl[l2];
                m.ttloc[idx] = 64 * m.ntrips[l];
                m.trip_of_l[l][m.ntrips[l]] = idx;
                m.ntrips[l]++;
                idx++;
            }
        }
    int so = 0, wo = 0;
    for (int l = 0; l < NL; l++) {
        m.mid_tau[l] = 64 * m.ntrips[l];
        m.std_off[l] = so; so += m.mid_tau[l];
        m.w_off[l]   = wo; wo += 8 * m.mid_tau[l];
    }
    // chunking (balanced) + greedy cost-balanced slot->wave assignment (16 bins)
    for (int l = 0; l < NL; l++) {
        const int TW = 2 * l + 1;
        const int maxslot = MID_LDS / (64 * TW);
        const int ntl = m.ntrips[l];
        const int nch = (ntl + maxslot - 1) / maxslot;
        m.nch[l] = nch;
        int done = 0;
        for (int c = 0; c < nch; c++) {
            int cnt = (ntl - done + (nch - c) - 1) / (nch - c);
            m.ch_start[l][c] = done; m.ch_cnt[l][c] = cnt; done += cnt;
        }
        for (int c = 0; c < nch; c++) {
            const int s0 = m.ch_start[l][c], cnt = m.ch_cnt[l][c];
            int cost[16] = {}; bool asg[16] = {};
            for (int i = 0; i < cnt; i++) {
                int trip = m.trip_of_l[l][s0 + i];
                int l1 = m.tl1[trip], l2 = m.tl2[trip];
                int tc = 0;
                for (int mi = 0; mi < TW; mi++) {
                    int base = mi - l;
                    int lo = base + l1 - l2; if (lo < 0) lo = 0;
                    int hi = base + l1 + l2; if (hi > 2 * l1) hi = 2 * l1;
                    tc += hi - lo + 1;
                }
                cost[i] = tc * 6 + (2 * l1 + 1 + 2 * l2 + 1) * 2;
            }
            int load[NWAVES] = {};
            for (int k = 0; k < cnt; k++) {
                int best = -1, bc = -1;
                for (int i = 0; i < cnt; i++)
                    if (!asg[i] && cost[i] > bc) { bc = cost[i]; best = i; }
                asg[best] = true;
                int wsel = 0;
                for (int w2 = 1; w2 < NWAVES; w2++) if (load[w2] < load[wsel]) wsel = w2;
                m.wave_of[l][s0 + best] = wsel;
                load[wsel] += bc;
            }
        }
    }
    return m;
}

constexpr Meta MT = build_meta();
constexpr int WLEN = 35328;  // complex weights
static_assert(MT.w_off[5] + 8 * MT.mid_tau[5] == WLEN, "wlen");
static_assert(MT.std_off[5] + MT.mid_tau[5] == 4416, "stdlen");

// redbuf: [parity][wave][m] float2, stride 11
constexpr int REDW = 11;
constexpr int REDBUF = 2 * NWAVES * REDW;   // 352 float2 = 2.8 KB

// ---------------------------------------------------- constexpr CG coeffs ---
constexpr double cfact(int n) {
    double r = 1.0;
    for (int i = 2; i <= n; i++) r *= (double)i;
    return r;
}
constexpr double csqrt(double x) {
    double g = x > 1.0 ? x : 1.0;
    for (int i = 0; i < 100; i++) g = 0.5 * (g + x / g);
    return g;
}
constexpr float cg_coeff(int l1, int l2, int l, int m1, int m2, int m) {
    if (m1 + m2 != m) return 0.0f;
    double pre = csqrt((double)(2 * l + 1) * cfact(l + l1 - l2) * cfact(l - l1 + l2) *
                       cfact(l1 + l2 - l) / cfact(l1 + l2 + l + 1));
    pre *= csqrt(cfact(l + m) * cfact(l - m) * cfact(l1 - m1) * cfact(l1 + m1) *
                 cfact(l2 - m2) * cfact(l2 + m2));
    double s = 0.0;
    for (int k = 0; k <= l1 + l2 - l; k++) {
        int d0 = k, d1 = l1 + l2 - l - k, d2 = l1 - m1 - k;
        int d3 = l2 + m2 - k, d4 = l - l2 + m1 + k, d5 = l - l1 - m2 + k;
        if (d0 < 0 || d1 < 0 || d2 < 0 || d3 < 0 || d4 < 0 || d5 < 0) continue;
        double den = cfact(d0) * cfact(d1) * cfact(d2) * cfact(d3) * cfact(d4) * cfact(d5);
        s += ((k & 1) ? -1.0 : 1.0) / den;
    }
    return (float)(pre * s);
}

// compile-time for
template <int... Is, class F>
__device__ __forceinline__ void static_for_impl(std::integer_sequence<int, Is...>, F&& f) {
    (f(std::integral_constant<int, Is>{}), ...);
}
template <int N, class F>
__device__ __forceinline__ void static_for(F&& f) {
    static_for_impl(std::make_integer_sequence<int, N>{}, (F&&)f);
}

// -------------------------------------------------------------- epilogue ----
// Combine (o, o+8) halves of l=P from redbuf and store. Runs on wave 15,
// inside a barrier region that follows P's redbuf write. 8*TWp can exceed
// 64 (P=4: 72, P=5: 88) -> lane-strided loop, not a single-shot guard.
template <int P>
__device__ __forceinline__ void epilogue(int b, int tid,
                                         const float2* __restrict__ redbuf,
                                         float2* __restrict__ out) {
    constexpr int TWp = 2 * P + 1;
    const int wid = tid >> 6, lane = tid & 63;
    if (wid == NWAVES - 1) {
#pragma unroll
        for (int i0 = 0; i0 < 8 * TWp; i0 += 64) {
            const int i = i0 + lane;
            if (i < 8 * TWp) {
                const int o = i / TWp, m = i % TWp;   // TWp constexpr -> magic mul
                const float2 a = redbuf[(P & 1) * NWAVES * REDW + o * REDW + m];
                const float2 c = redbuf[(P & 1) * NWAVES * REDW + (o + 8) * REDW + m];
                out[(size_t)b * ROW + MT.f_l[P] + o * TWp + m] =
                    make_float2(a.x + c.x, a.y + c.y);
            }
        }
    }
}

// ------------------------------------------------------------- main kernel --
template <int L>
__device__ __forceinline__ void process_l(int b, int tid,
                                          const float2* __restrict__ F,
                                          float2* __restrict__ mid,
                                          const float2* __restrict__ w,
                                          const float* __restrict__ stdv,
                                          float2* __restrict__ out,
                                          float2* __restrict__ redbuf) {
    constexpr int TW  = 2 * L + 1;
    constexpr int NCH = MT.nch[L];
    constexpr int NT  = MT.mid_tau[L];

    const int wid  = tid >> 6;     // wave 0..15
    const int lane = tid & 63;     // stage1: ts = (t,s); stage2: T-lane
    const int t = lane >> 3, s = lane & 7;

    float2 acc[TW];                // one o = wid&7, T-half = wid>>3
#pragma unroll
    for (int i = 0; i < TW; i++) acc[i] = make_float2(0.f, 0.f);

    static_for<NCH>([&](auto CHc) {
        constexpr int CH  = decltype(CHc)::value;
        constexpr int S0  = MT.ch_start[L][CH];
        constexpr int CNT = MT.ch_cnt[L][CH];
        constexpr int CT  = CNT * 64;            // T extent of this chunk
        static_assert(CT * TW <= MID_LDS, "chunk fits");

        __syncthreads();   // previous consumers of `mid` done (covers F load too)

        // previous l's output combine rides in this region (wave 15 only)
        if constexpr (CH == 0 && L > 0)
            epilogue<L - 1>(b, tid, redbuf, out);

        // ---- stage 1: mid[m][T] for slots [S0, S0+CNT), scaled by 1/std --
        static_for<CNT>([&](auto SIc) {
            constexpr int SI   = S0 + decltype(SIc)::value;
            constexpr int TRIP = MT.trip_of_l[L][SI];
            constexpr int L1   = MT.tl1[TRIP];
            constexpr int L2v  = MT.tl2[TRIP];
            constexpr int N1   = 2 * L1 + 1, N2 = 2 * L2v + 1;
            if (MT.wave_of[L][SI] == wid) {
                const float inv = 1.0f /
                    (stdv[MT.std_off[L] + MT.ttloc[TRIP] + lane] + 1e-5f);
                const float2* F1 = F + MT.tf1[TRIP] + t * N1;
                const float2* F2 = F + MT.tf2[TRIP] + s * N2;
                float2 f1[N1], f2[N2];
#pragma unroll
                for (int i = 0; i < N1; i++) f1[i] = F1[i];
#pragma unroll
                for (int i = 0; i < N2; i++) f2[i] = F2[i];
                const int Tloc = (MT.ttloc[TRIP] - S0 * 64) + lane;
                static_for<TW>([&](auto MIc) {
                    constexpr int MI   = decltype(MIc)::value;
                    constexpr int BASE = MI - L;   // m
                    constexpr int LO_  = BASE + L1 - L2v;
                    constexpr int LO   = LO_ < 0 ? 0 : LO_;
                    constexpr int HI_  = BASE + L1 + L2v;
                    constexpr int HI   = HI_ > 2 * L1 ? 2 * L1 : HI_;
                    float re = 0.f, im = 0.f;
                    static_for<HI - LO + 1>([&](auto Kc) {
                        constexpr int AI = LO + decltype(Kc)::value;
                        constexpr int CI = BASE + L1 + L2v - AI;
                        constexpr float cv = cg_coeff(L1, L2v, L, AI - L1, CI - L2v, BASE);
                        if constexpr (cv != 0.0f) {
                            const float2 a = f1[AI], c2 = f2[CI];
                            re = fmaf(cv, fmaf(-a.y, c2.y, a.x * c2.x), re);
                            im = fmaf(cv, fmaf(a.y, c2.x, a.x * c2.y), im);
                        }
                    });
                    mid[MI * CT + Tloc] = make_float2(re * inv, im * inv);
                });
            }
        });
        __syncthreads();

        // ---- stage 2: acc[m] += sum_T W[o,T]*mid[m][T]; 1 o, half T ------
        // R4-verified form: rolled runtime loop, loads in-loop, inline body.
        {
            const int o = wid & 7, half = wid >> 3;
            const float2* W0 = w + MT.w_off[L] + o * NT + S0 * 64;
            for (int T = lane * 2 + half * 128; T < CT; T += 256) {
                const float4 w0 = *reinterpret_cast<const float4*>(W0 + T);
#pragma unroll
                for (int mi = 0; mi < TW; mi++) {
                    const float4 mv = *reinterpret_cast<const float4*>(mid + mi * CT + T);
                    acc[mi].x = fmaf(w0.x, mv.x, fmaf(-w0.y, mv.y,
                                  fmaf(w0.z, mv.z, fmaf(-w0.w, mv.w, acc[mi].x))));
                    acc[mi].y = fmaf(w0.x, mv.y, fmaf(w0.y, mv.x,
                                  fmaf(w0.z, mv.w, fmaf(w0.w, mv.z, acc[mi].y))));
                }
            }
        }
    });

    // full 64-lane butterfly per wave; lane0 publishes to redbuf
    float2 red[TW];
#pragma unroll
    for (int mi = 0; mi < TW; mi++) {
        float rx = acc[mi].x, ry = acc[mi].y;
#pragma unroll
        for (int off = 32; off >= 1; off >>= 1) {
            rx += __shfl_xor(rx, off, 64);
            ry += __shfl_xor(ry, off, 64);
        }
        red[mi] = make_float2(rx, ry);
    }
    if (lane == 0) {
#pragma unroll
        for (int mi = 0; mi < TW; mi++)
            redbuf[(L & 1) * NWAVES * REDW + wid * REDW + mi] = red[mi];
    }
}

__global__ __launch_bounds__(1024, 4) void fup_main(const float2* __restrict__ act,
                                                    const float2* __restrict__ w,
                                                    const float* __restrict__ stdv,
                                                    float2* __restrict__ out) {
    __shared__ float2 F[ROW];
    __shared__ __align__(16) float2 mid[MID_LDS];
    __shared__ float2 redbuf[REDBUF];
    const int b = blockIdx.x;
    const int tid = threadIdx.x;
    const float2* arow = act + (size_t)b * ROW;
    for (int i = tid; i < ROW; i += 1024) F[i] = arow[i];
    // sync happens at top of first chunk inside process_l<0>
    process_l<0>(b, tid, F, mid, w, stdv, out, redbuf);
    process_l<1>(b, tid, F, mid, w, stdv, out, redbuf);
    process_l<2>(b, tid, F, mid, w, stdv, out, redbuf);
    process_l<3>(b, tid, F, mid, w, stdv, out, redbuf);
    process_l<4>(b, tid, F, mid, w, stdv, out, redbuf);
    process_l<5>(b, tid, F, mid, w, stdv, out, redbuf);
    __syncthreads();
    epilogue<5>(b, tid, redbuf, out);
}

// ----------------------------------------------------------------- launch ---
extern "C" void kernel_launch(void* const* d_in, const int* in_sizes, int n_in,
                              void* d_out, int out_size, void* d_ws, size_t ws_size,
                              hipStream_t stream) {
    const float2* act  = (const float2*)d_in[0];
    const float2* wts  = (const float2*)d_in[1];
    const float*  stdv = (const float*)d_in[2];
    float2* out = (float2*)d_out;
    (void)d_ws; (void)ws_size;

    hipLaunchKernelGGL(fup_main, dim3(BATCH), dim3(1024), 0, stream,
                       act, wts, stdv, out);
}

// Round 8
// 122.574 us; speedup vs baseline: 1.5989x; 1.5989x over previous
//
#include <hip/hip_runtime.h>
#include <hip/hip_bf16.h>
#include <utility>

// fUpModule CG tensor product, MAXL=5, TAUS=OUT_TAUS=8, BATCH=1024, fp32 I/O.
// R12: two independent R4-pipelines per block. 512-thread blocks, 8 waves:
// waves 0-3 process batch row 2*bid in mid[0]/F[0]; waves 4-7 process row
// 2*bid+1 in mid[1]/F[1]. Per-wave inner code is BYTE-IDENTICAL to the
// verified-clean R4 form (4-wave greedy stage-1; rolled stage-2 loop with
// in-loop W loads shared across 2 o's; merge-shuffle reduce) + std-fold
// (validated R6). Why: R11 proved mega-blocks destroy per-wave efficiency
// (o-split doubled LDS reads; 16-wave barriers idle); R9 proved more small
// blocks don't raise residency. This keeps R4 per-wave efficiency exactly,
// halves barriers-per-row (18 per 2 rows), and fits 2 blocks/CU at 70.5 KiB
// -> whole grid (512 blocks) co-resident = 16 waves/CU vs R4's ~10.
// Identical instruction streams in both halves -> barrier skew unchanged.
// R5-R8 lessons: no asm barriers, no register arrays through lambda refs,
// no launch_bounds caps below need ((512,4) -> cap 128, code needs 64).

constexpr int NTRIP = 69;
constexpr int NL    = 6;
constexpr int BATCH = 1024;
constexpr int ROW   = 288;     // complex elements per activation/output row
constexpr int MID_LDS = 4224;  // float2 slots per mid buffer (x2 buffers)

struct Meta {
    int tl1[NTRIP], tl2[NTRIP], tll[NTRIP];
    int tf1[NTRIP], tf2[NTRIP];   // complex offsets of F[l1], F[l2] blocks
    int ttloc[NTRIP];             // T start of this triple within its l group
    int trip_of_l[NL][16];
    int ntrips[NL];
    int mid_tau[NL], std_off[NL], w_off[NL], f_l[NL];
    int nch[NL];
    int ch_start[NL][2], ch_cnt[NL][2];
    int wave_of[NL][16];
};

constexpr Meta build_meta() {
    Meta m{};
    int fl[NL] = {};
    {
        int acc = 0;
        for (int l = 0; l < NL; l++) { fl[l] = acc; m.f_l[l] = acc; acc += 8 * (2 * l + 1); }
    }
    int idx = 0;
    for (int l1 = 0; l1 <= 5; l1++)
        for (int l2 = 0; l2 <= l1; l2++) {
            int lmax = (l1 + l2 < 5) ? (l1 + l2) : 5;
            for (int l = l1 - l2; l <= lmax; l++) {
                m.tl1[idx] = l1; m.tl2[idx] = l2; m.tll[idx] = l;
                m.tf1[idx] = fl[l1]; m.tf2[idx] = fl[l2];
                m.ttloc[idx] = 64 * m.ntrips[l];
                m.trip_of_l[l][m.ntrips[l]] = idx;
                m.ntrips[l]++;
                idx++;
            }
        }
    int so = 0, wo = 0;
    for (int l = 0; l < NL; l++) {
        m.mid_tau[l] = 64 * m.ntrips[l];
        m.std_off[l] = so; so += m.mid_tau[l];
        m.w_off[l]   = wo; wo += 8 * m.mid_tau[l];
    }
    // chunking (balanced) + greedy cost-balanced slot->wave assignment (4 bins)
    for (int l = 0; l < NL; l++) {
        const int TW = 2 * l + 1;
        const int maxslot = MID_LDS / (64 * TW);
        const int ntl = m.ntrips[l];
        const int nch = (ntl + maxslot - 1) / maxslot;
        m.nch[l] = nch;
        int done = 0;
        for (int c = 0; c < nch; c++) {
            int cnt = (ntl - done + (nch - c) - 1) / (nch - c);
            m.ch_start[l][c] = done; m.ch_cnt[l][c] = cnt; done += cnt;
        }
        for (int c = 0; c < nch; c++) {
            const int s0 = m.ch_start[l][c], cnt = m.ch_cnt[l][c];
            int cost[16] = {}; bool asg[16] = {};
            for (int i = 0; i < cnt; i++) {
                int trip = m.trip_of_l[l][s0 + i];
                int l1 = m.tl1[trip], l2 = m.tl2[trip];
                int tc = 0;
                for (int mi = 0; mi < TW; mi++) {
                    int base = mi - l;
                    int lo = base + l1 - l2; if (lo < 0) lo = 0;
                    int hi = base + l1 + l2; if (hi > 2 * l1) hi = 2 * l1;
                    tc += hi - lo + 1;
                }
                cost[i] = tc * 6 + (2 * l1 + 1 + 2 * l2 + 1) * 2;
            }
            int load[4] = {};
            for (int k = 0; k < cnt; k++) {
                int best = -1, bc = -1;
                for (int i = 0; i < cnt; i++)
                    if (!asg[i] && cost[i] > bc) { bc = cost[i]; best = i; }
                asg[best] = true;
                int wsel = 0;
                for (int w2 = 1; w2 < 4; w2++) if (load[w2] < load[wsel]) wsel = w2;
                m.wave_of[l][s0 + best] = wsel;
                load[wsel] += bc;
            }
        }
    }
    return m;
}

constexpr Meta MT = build_meta();
constexpr int WLEN = 35328;  // complex weights
static_assert(MT.w_off[5] + 8 * MT.mid_tau[5] == WLEN, "wlen");
static_assert(MT.std_off[5] + MT.mid_tau[5] == 4416, "stdlen");

// ---------------------------------------------------- constexpr CG coeffs ---
constexpr double cfact(int n) {
    double r = 1.0;
    for (int i = 2; i <= n; i++) r *= (double)i;
    return r;
}
constexpr double csqrt(double x) {
    double g = x > 1.0 ? x : 1.0;
    for (int i = 0; i < 100; i++) g = 0.5 * (g + x / g);
    return g;
}
constexpr float cg_coeff(int l1, int l2, int l, int m1, int m2, int m) {
    if (m1 + m2 != m) return 0.0f;
    double pre = csqrt((double)(2 * l + 1) * cfact(l + l1 - l2) * cfact(l - l1 + l2) *
                       cfact(l1 + l2 - l) / cfact(l1 + l2 + l + 1));
    pre *= csqrt(cfact(l + m) * cfact(l - m) * cfact(l1 - m1) * cfact(l1 + m1) *
                 cfact(l2 - m2) * cfact(l2 + m2));
    double s = 0.0;
    for (int k = 0; k <= l1 + l2 - l; k++) {
        int d0 = k, d1 = l1 + l2 - l - k, d2 = l1 - m1 - k;
        int d3 = l2 + m2 - k, d4 = l - l2 + m1 + k, d5 = l - l1 - m2 + k;
        if (d0 < 0 || d1 < 0 || d2 < 0 || d3 < 0 || d4 < 0 || d5 < 0) continue;
        double den = cfact(d0) * cfact(d1) * cfact(d2) * cfact(d3) * cfact(d4) * cfact(d5);
        s += ((k & 1) ? -1.0 : 1.0) / den;
    }
    return (float)(pre * s);
}

// compile-time for
template <int... Is, class F>
__device__ __forceinline__ void static_for_impl(std::integer_sequence<int, Is...>, F&& f) {
    (f(std::integral_constant<int, Is>{}), ...);
}
template <int N, class F>
__device__ __forceinline__ void static_for(F&& f) {
    static_for_impl(std::make_integer_sequence<int, N>{}, (F&&)f);
}

// ------------------------------------------------------------- main kernel --
// Per-4-wave-group pipeline; tid is the thread id WITHIN the group (0..255).
// Byte-identical to the verified-clean R4 form (+ std-fold).
template <int L>
__device__ __forceinline__ void process_l(int b, int tid,
                                          const float2* __restrict__ F,
                                          float2* __restrict__ mid,
                                          const float2* __restrict__ w,
                                          const float* __restrict__ stdv,
                                          float2* __restrict__ out) {
    constexpr int TW  = 2 * L + 1;
    constexpr int NCH = MT.nch[L];
    constexpr int NT  = MT.mid_tau[L];

    const int wid  = tid >> 6;     // wave 0..3 within group
    const int lane = tid & 63;     // stage1: ts = (t,s); stage2: T-lane
    const int t = lane >> 3, s = lane & 7;

    float2 acc0[TW], acc1[TW];     // o = wid, o = wid + 4
#pragma unroll
    for (int i = 0; i < TW; i++) { acc0[i] = make_float2(0.f, 0.f); acc1[i] = make_float2(0.f, 0.f); }

    static_for<NCH>([&](auto CHc) {
        constexpr int CH  = decltype(CHc)::value;
        constexpr int S0  = MT.ch_start[L][CH];
        constexpr int CNT = MT.ch_cnt[L][CH];
        constexpr int CT  = CNT * 64;            // T extent of this chunk
        static_assert(CT * TW <= MID_LDS, "chunk fits");

        __syncthreads();   // previous consumers of `mid` done (covers F load too)

        // ---- stage 1: mid[m][T] for slots [S0, S0+CNT), scaled by 1/std --
        static_for<CNT>([&](auto SIc) {
            constexpr int SI   = S0 + decltype(SIc)::value;
            constexpr int TRIP = MT.trip_of_l[L][SI];
            constexpr int L1   = MT.tl1[TRIP];
            constexpr int L2v  = MT.tl2[TRIP];
            constexpr int N1   = 2 * L1 + 1, N2 = 2 * L2v + 1;
            if (MT.wave_of[L][SI] == wid) {
                const float inv = 1.0f /
                    (stdv[MT.std_off[L] + MT.ttloc[TRIP] + lane] + 1e-5f);
                const float2* F1 = F + MT.tf1[TRIP] + t * N1;
                const float2* F2 = F + MT.tf2[TRIP] + s * N2;
                float2 f1[N1], f2[N2];
#pragma unroll
                for (int i = 0; i < N1; i++) f1[i] = F1[i];
#pragma unroll
                for (int i = 0; i < N2; i++) f2[i] = F2[i];
                const int Tloc = (MT.ttloc[TRIP] - S0 * 64) + lane;
                static_for<TW>([&](auto MIc) {
                    constexpr int MI   = decltype(MIc)::value;
                    constexpr int BASE = MI - L;   // m
                    constexpr int LO_  = BASE + L1 - L2v;
                    constexpr int LO   = LO_ < 0 ? 0 : LO_;
                    constexpr int HI_  = BASE + L1 + L2v;
                    constexpr int HI   = HI_ > 2 * L1 ? 2 * L1 : HI_;
                    float re = 0.f, im = 0.f;
                    static_for<HI - LO + 1>([&](auto Kc) {
                        constexpr int AI = LO + decltype(Kc)::value;
                        constexpr int CI = BASE + L1 + L2v - AI;
                        constexpr float cv = cg_coeff(L1, L2v, L, AI - L1, CI - L2v, BASE);
                        if constexpr (cv != 0.0f) {
                            const float2 a = f1[AI], c2 = f2[CI];
                            re = fmaf(cv, fmaf(-a.y, c2.y, a.x * c2.x), re);
                            im = fmaf(cv, fmaf(a.y, c2.x, a.x * c2.y), im);
                        }
                    });
                    mid[MI * CT + Tloc] = make_float2(re * inv, im * inv);
                });
            }
        });
        __syncthreads();

        // ---- stage 2: acc[o,m] += sum_T W[o,T]*mid[m][T]; 2 o's, 2 T's --
        // R4-verified form: rolled runtime loop, loads in-loop, inline body.
        {
            const float2* W0 = w + MT.w_off[L] + wid * NT + S0 * 64;
            const float2* W1 = w + MT.w_off[L] + (wid + 4) * NT + S0 * 64;
            for (int T = lane * 2; T < CT; T += 128) {
                const float4 w0 = *reinterpret_cast<const float4*>(W0 + T);
                const float4 w1 = *reinterpret_cast<const float4*>(W1 + T);
#pragma unroll
                for (int mi = 0; mi < TW; mi++) {
                    const float4 mv = *reinterpret_cast<const float4*>(mid + mi * CT + T);
                    acc0[mi].x = fmaf(w0.x, mv.x, fmaf(-w0.y, mv.y,
                                  fmaf(w0.z, mv.z, fmaf(-w0.w, mv.w, acc0[mi].x))));
                    acc0[mi].y = fmaf(w0.x, mv.y, fmaf(w0.y, mv.x,
                                  fmaf(w0.z, mv.w, fmaf(w0.w, mv.z, acc0[mi].y))));
                    acc1[mi].x = fmaf(w1.x, mv.x, fmaf(-w1.y, mv.y,
                                  fmaf(w1.z, mv.z, fmaf(-w1.w, mv.w, acc1[mi].x))));
                    acc1[mi].y = fmaf(w1.x, mv.y, fmaf(w1.y, mv.x,
                                  fmaf(w1.z, mv.w, fmaf(w1.w, mv.z, acc1[mi].y))));
                }
            }
        }
    });

    // merge-reduce: lo half ends with sum for o=wid, hi half for o=wid+4
    const bool lo = (lane < 32);
    float2 red[TW];
#pragma unroll
    for (int mi = 0; mi < TW; mi++) {
        float gx = lo ? acc1[mi].x : acc0[mi].x;   // value to give away
        float gy = lo ? acc1[mi].y : acc0[mi].y;
        float rx = (lo ? acc0[mi].x : acc1[mi].x) + __shfl_xor(gx, 32, 64);
        float ry = (lo ? acc0[mi].y : acc1[mi].y) + __shfl_xor(gy, 32, 64);
#pragma unroll
        for (int off = 16; off >= 1; off >>= 1) {
            rx += __shfl_xor(rx, off, 64);
            ry += __shfl_xor(ry, off, 64);
        }
        red[mi] = make_float2(rx, ry);
    }
    if (lane == 0 || lane == 32) {
        const int o = wid + (lo ? 0 : 4);
        float2* orow = out + (size_t)b * ROW + MT.f_l[L] + o * TW;
#pragma unroll
        for (int mi = 0; mi < TW; mi++) orow[mi] = red[mi];
    }
}

__global__ __launch_bounds__(512, 4) void fup_main(const float2* __restrict__ act,
                                                   const float2* __restrict__ w,
                                                   const float* __restrict__ stdv,
                                                   float2* __restrict__ out) {
    __shared__ float2 F[2][ROW];
    __shared__ __align__(16) float2 mid[2][MID_LDS];
    const int half = threadIdx.x >> 8;          // 0: waves 0-3, 1: waves 4-7
    const int tidg = threadIdx.x & 255;         // tid within the 4-wave group
    const int b    = (blockIdx.x << 1) | half;  // one batch row per group
    float2* midh = mid[half];
    float2* Fh   = F[half];
    const float2* arow = act + (size_t)b * ROW;
    for (int i = tidg; i < ROW; i += 256) Fh[i] = arow[i];
    // sync happens at top of first chunk inside process_l<0>
    process_l<0>(b, tidg, Fh, midh, w, stdv, out);
    process_l<1>(b, tidg, Fh, midh, w, stdv, out);
    process_l<2>(b, tidg, Fh, midh, w, stdv, out);
    process_l<3>(b, tidg, Fh, midh, w, stdv, out);
    process_l<4>(b, tidg, Fh, midh, w, stdv, out);
    process_l<5>(b, tidg, Fh, midh, w, stdv, out);
}

// ----------------------------------------------------------------- launch ---
extern "C" void kernel_launch(void* const* d_in, const int* in_sizes, int n_in,
                              void* d_out, int out_size, void* d_ws, size_t ws_size,
                              hipStream_t stream) {
    const float2* act  = (const float2*)d_in[0];
    const float2* wts  = (const float2*)d_in[1];
    const float*  stdv = (const float*)d_in[2];
    float2* out = (float2*)d_out;
    (void)d_ws; (void)ws_size;

    hipLaunchKernelGGL(fup_main, dim3(BATCH / 2), dim3(512), 0, stream,
                       act, wts, stdv, out);
}